// Round 5
// baseline (96.103 us; speedup 1.0000x reference)
//
#include <hip/hip_runtime.h>

#define S 32
#define E 48
#define H 512
#define L 16

typedef float vf4 __attribute__((ext_vector_type(4)));

// ws layout (floats):
//   [0, S*E*L)        xa : exp(2*a[s,e,l])
//   [S*E*L, 2*S*E*L)  xb : exp(2*b[s,e,l] + bias[l] - p2[l])

// Fused stats + dots, 3 se-rows per block: 4 waves, wave w owns l = 4w..4w+3.
__global__ __launch_bounds__(256) void k1_fused(const float* __restrict__ emb,
                                                const float* __restrict__ proto,
                                                const float* __restrict__ ic,
                                                float* __restrict__ xa,
                                                float* __restrict__ xb) {
    int b    = blockIdx.x;         // 0 .. 511
    int t    = threadIdx.x;
    int wid  = t >> 6;             // 0..3
    int lane = t & 63;
    int se0  = b * 3;

    float4 e0[3], e1[3];
#pragma unroll
    for (int r = 0; r < 3; ++r) {
        const float* er = emb + (size_t)(se0 + r) * H;
        e0[r] = *reinterpret_cast<const float4*>(er + 4 * lane);
        e1[r] = *reinterpret_cast<const float4*>(er + 256 + 4 * lane);
    }

    float my_a[3] = {0.f, 0.f, 0.f};
    float my_b[3] = {0.f, 0.f, 0.f};
    float my_p    = 0.f;

#pragma unroll
    for (int i = 0; i < 4; ++i) {
        int l = wid * 4 + i;
        const float* ph = proto + (size_t)l * (2 * H);   // head [0,512)
        const float* pt = ph + H;                        // tail [512,1024)
        float4 h0 = *reinterpret_cast<const float4*>(ph + 4 * lane);
        float4 h1 = *reinterpret_cast<const float4*>(ph + 256 + 4 * lane);
        float4 t0 = *reinterpret_cast<const float4*>(pt + 4 * lane);
        float4 t1 = *reinterpret_cast<const float4*>(pt + 256 + 4 * lane);

        float da[3], db[3];
#pragma unroll
        for (int r = 0; r < 3; ++r) {
            da[r] = e0[r].x * h0.x + e0[r].y * h0.y + e0[r].z * h0.z + e0[r].w * h0.w
                  + e1[r].x * h1.x + e1[r].y * h1.y + e1[r].z * h1.z + e1[r].w * h1.w;
            db[r] = e0[r].x * t0.x + e0[r].y * t0.y + e0[r].z * t0.z + e0[r].w * t0.w
                  + e1[r].x * t1.x + e1[r].y * t1.y + e1[r].z * t1.z + e1[r].w * t1.w;
        }
        float dp = h0.x * h0.x + h0.y * h0.y + h0.z * h0.z + h0.w * h0.w
                 + h1.x * h1.x + h1.y * h1.y + h1.z * h1.z + h1.w * h1.w
                 + t0.x * t0.x + t0.y * t0.y + t0.z * t0.z + t0.w * t0.w
                 + t1.x * t1.x + t1.y * t1.y + t1.z * t1.z + t1.w * t1.w;
#pragma unroll
        for (int m = 32; m >= 1; m >>= 1) {
#pragma unroll
            for (int r = 0; r < 3; ++r) {
                da[r] += __shfl_xor(da[r], m);
                db[r] += __shfl_xor(db[r], m);
            }
            dp += __shfl_xor(dp, m);
        }
        if (lane == i) {
#pragma unroll
            for (int r = 0; r < 3; ++r) { my_a[r] = da[r]; my_b[r] = db[r]; }
            my_p = dp;
        }
    }

    if (lane < 4) {
        int l = wid * 4 + lane;
        float total = 0.f;
#pragma unroll
        for (int k = 0; k < L; ++k) total += ic[k];
        float icl  = ic[l];
        float bias = icl / (total - icl);
#pragma unroll
        for (int r = 0; r < 3; ++r) {
            xa[(size_t)(se0 + r) * L + l] = __expf(2.f * my_a[r]);
            xb[(size_t)(se0 + r) * L + l] = __expf(2.f * my_b[r] + bias - my_p);
        }
    }
}

// one block per (s,e1): max-free softmax via xa*xb products, stream 48KB out
__global__ __launch_bounds__(256) void k2_softmax(const float* __restrict__ xa,
                                                  const float* __restrict__ xb,
                                                  float* __restrict__ out) {
    int e1 = blockIdx.x;          // 0..47
    int s  = blockIdx.y;          // 0..31
    int t  = threadIdx.x;

    __shared__ float hs[L];            // xa row for (s,e1)
    __shared__ float hbL[E][L];        // xb panel for s (48 x 16)
    __shared__ float pred[E][L];       // softmax rows

    if (t < L) hs[t] = xa[(s * E + e1) * L + t];
    if (t < (E * L) / 4) {             // 192 float4 loads, contiguous
        float4 v = reinterpret_cast<const float4*>(xb + (size_t)s * E * L)[t];
        reinterpret_cast<float4*>(&hbL[0][0])[t] = v;
    }
    __syncthreads();

    if (t < E) {                       // thread t owns softmax row e2 = t
        float pr[L];
        float sum = 0.f;
#pragma unroll
        for (int l = 0; l < L; ++l) {
            pr[l] = hs[l] * hbL[t][l];
            sum += pr[l];
        }
        float inv = (t == e1) ? 0.f : 1.f / sum;   // diagonal -> zero row
#pragma unroll
        for (int l = 0; l < L; ++l) pred[t][l] = pr[l] * inv;
    }
    __syncthreads();

    // (s,e1) owns 48 output rows x 256 floats = 3072 float4s, contiguous
    vf4* o4 = reinterpret_cast<vf4*>(out) + (size_t)(s * E + e1) * E * 64;
#pragma unroll
    for (int j = 0; j < 12; ++j) {
        int idx4 = j * 256 + t;
        int row = idx4 >> 6;                       // wave-uniform
        vf4 v = *(reinterpret_cast<const vf4*>(&pred[row][0]) + (idx4 & 3));
        __builtin_nontemporal_store(v, o4 + idx4);
    }
}

extern "C" void kernel_launch(void* const* d_in, const int* in_sizes, int n_in,
                              void* d_out, int out_size, void* d_ws, size_t ws_size,
                              hipStream_t stream) {
    const float* emb   = (const float*)d_in[0];   // (S,E,H)
    const float* proto = (const float*)d_in[1];   // (L,2H)
    const float* ic    = (const float*)d_in[2];   // (L,)
    float* out = (float*)d_out;

    float* ws = (float*)d_ws;
    float* xa = ws;
    float* xb = ws + S * E * L;

    k1_fused<<<S * E / 3, 256, 0, stream>>>(emb, proto, ic, xa, xb);
    dim3 g2(E, S);
    k2_softmax<<<g2, 256, 0, stream>>>(xa, xb, out);
}